// Round 11
// baseline (84.610 us; speedup 1.0000x reference)
//
#include <hip/hip_runtime.h>
#include <hip/hip_bf16.h>
#include <cstdint>

// DLM breadth-2 forward. B=16, n=128, C=64.
// out = [out0 (16*64) | out1 (16*128*64) | out2 (16*128*128*64)], fp32.
//
// out2[b,i,j,c] = sigmoid( PA[b,i,c] + PB[b,j,c]
//                          + x2[b,i,j,:]·W2[64:128,c] + x2[b,j,i,:]·W2[192:256,c] )
// with PA = x1·W2[0:64] + b2, PB = x1·W2[128:192]  (precomputed).
//
// k_main (R8 structure + 4-unit software pipeline): grid 1024 x 128thr;
// each block runs 4 consecutive (b,i,half) units. Per unit: issue vb ->
// consume prefetched va (maxmin/pack/reduce) -> issue NEXT unit's va ->
// pack vb -> MFMA -> epilogue. Next-unit loads fly under MFMA+sigmoid
// epilogue -> loads stay outstanding through the block lifetime
// (burst-smoothing). Ald (16KB) reused across units: per-wave in-order
// LDS + the per-unit lgkm fence make it race-free without barriers.

#define NDIM 128
#define CDIM 64

typedef float f32x4 __attribute__((ext_vector_type(4)));
typedef short s16x8 __attribute__((ext_vector_type(8)));

__device__ __forceinline__ unsigned short f2bf(float f) {
    union { float f; unsigned int u; } v; v.f = f;
    unsigned int u = v.u;
    return (unsigned short)((u + 0x7FFFu + ((u >> 16) & 1u)) >> 16);  // RNE
}
__device__ __forceinline__ float sigmoidf_(float x) {
    return 1.0f / (1.0f + __expf(-x));
}
// pack float4 -> 4 bf16 (RNE) in two v_cvt_pk_bf16_f32
__device__ __forceinline__ uint2 pk4(float4 v) {
    unsigned lo, hi;
    asm("v_cvt_pk_bf16_f32 %0, %1, %2" : "=v"(lo) : "v"(v.x), "v"(v.y));
    asm("v_cvt_pk_bf16_f32 %0, %1, %2" : "=v"(hi) : "v"(v.z), "v"(v.w));
    uint2 r; r.x = lo; r.y = hi; return r;
}

// ---- merged prep: blocks [0,512) -> PA/PB; [512,544) -> WT; [544,560) -> out0
__global__ __launch_bounds__(256) void k_prep(const float* __restrict__ x0,
        const float* __restrict__ x1, const float* __restrict__ W0,
        const float* __restrict__ b0, const float* __restrict__ W2,
        const float* __restrict__ b2, float* __restrict__ PA,
        float* __restrict__ PB, unsigned short* __restrict__ WT,
        float* __restrict__ out0) {
    int bb = blockIdx.x;
    int t = threadIdx.x;
    if (bb < 512) {
        int u = t >> 6, c = t & 63;
        int blk = bb * 4 + u;          // 0..2047
        __shared__ float xv[4][64];
        xv[u][c] = x1[blk * 64 + c];   // wave-local RAW
        float accA = b2[c];
        float accB = 0.f;
#pragma unroll 8
        for (int k = 0; k < 64; ++k) {
            float xk = xv[u][k];
            accA += xk * W2[k * 64 + c];
            accB += xk * W2[(128 + k) * 64 + c];
        }
        PA[blk * 64 + c] = accA;
        PB[blk * 64 + c] = accB;
    } else if (bb < 544) {
        int idx = (bb - 512) * 256 + t;   // 0..8191
        int n = idx >> 7, k = idx & 127;
        int row = (k < 64) ? (64 + k) : (128 + k);
        WT[idx] = f2bf(W2[row * 64 + n]);
    } else {
        int b = bb - 544;
        int lane = t & 63, w = t >> 6;
        int q = lane & 15;
        int jq = lane >> 4;
        __shared__ float pw[4][64], pn[4][64], f0[136], spart[4][64];
        f32x4 mx = {-1e30f, -1e30f, -1e30f, -1e30f};
        f32x4 mn = {1e30f, 1e30f, 1e30f, 1e30f};
#pragma unroll
        for (int p = 0; p < 8; ++p) {
            int j = (w * 4 + jq) + 16 * p;
            float4 v = *reinterpret_cast<const float4*>(
                x1 + ((size_t)(b * 128 + j)) * 64 + q * 4);
            mx.x = fmaxf(mx.x, v.x); mx.y = fmaxf(mx.y, v.y);
            mx.z = fmaxf(mx.z, v.z); mx.w = fmaxf(mx.w, v.w);
            mn.x = fminf(mn.x, v.x); mn.y = fminf(mn.y, v.y);
            mn.z = fminf(mn.z, v.z); mn.w = fminf(mn.w, v.w);
        }
#pragma unroll
        for (int d = 16; d <= 32; d <<= 1) {
            mx.x = fmaxf(mx.x, __shfl_xor(mx.x, d)); mx.y = fmaxf(mx.y, __shfl_xor(mx.y, d));
            mx.z = fmaxf(mx.z, __shfl_xor(mx.z, d)); mx.w = fmaxf(mx.w, __shfl_xor(mx.w, d));
            mn.x = fminf(mn.x, __shfl_xor(mn.x, d)); mn.y = fminf(mn.y, __shfl_xor(mn.y, d));
            mn.z = fminf(mn.z, __shfl_xor(mn.z, d)); mn.w = fminf(mn.w, __shfl_xor(mn.w, d));
        }
        if (lane < 16) {
            *reinterpret_cast<f32x4*>(&pw[w][lane * 4]) = mx;
            *reinterpret_cast<f32x4*>(&pn[w][lane * 4]) = mn;
        }
        __syncthreads();
        if (t < 64) {
            int c = t;
            float M = fmaxf(fmaxf(pw[0][c], pw[1][c]), fmaxf(pw[2][c], pw[3][c]));
            float m = fminf(fminf(pn[0][c], pn[1][c]), fminf(pn[2][c], pn[3][c]));
            f0[8 + c] = M; f0[72 + c] = m;
            if (c < 8) f0[c] = x0[b * 8 + c];
        }
        __syncthreads();
        {
            int g = t >> 6, c = t & 63;
            float acc = 0.f;
#pragma unroll
            for (int k = g * 34; k < g * 34 + 34; ++k) acc += f0[k] * W0[k * 64 + c];
            spart[g][c] = acc;
        }
        __syncthreads();
        if (t < 64) {
            int c = t;
            out0[b * 64 + c] = sigmoidf_(
                spart[0][c] + spart[1][c] + spart[2][c] + spart[3][c] + b0[c]);
        }
    }
}

// ---- main: 4 pipelined units per block. 128 threads, 16KB LDS.
__global__ __launch_bounds__(128) void k_main(const float* __restrict__ x2,
        const unsigned short* __restrict__ WT,
        const float* __restrict__ PA, const float* __restrict__ PB,
        float* __restrict__ pmax_ws, float* __restrict__ pmin_ws,
        float* __restrict__ out2) {
    int t = threadIdx.x;
    int lane = t & 63, w = t >> 6; // w in 0..1
    int jq = lane >> 4;            // 0..3
    int l15 = lane & 15;
    int cc = l15 * 4;              // c-quad base
    int bid4 = blockIdx.x << 2;    // first unit (blk2) of this block

    __shared__ __align__(16) unsigned short Ald[64 * 128];   // 16KB, XOR-swizzled

    // ---- prologue: prefetch unit 0's xa
    float4 vaP[8];
    {
        int blk2 = bid4;
        int blk = blk2 >> 1, half = blk2 & 1;
        const float* xaSrc = x2 + (size_t)blk * (NDIM * CDIM) + ((half << 6) * 64);
#pragma unroll
        for (int p = 0; p < 8; ++p) {
            int jl = 32 * w + p * 4 + jq;
            vaP[p] = *reinterpret_cast<const float4*>(xaSrc + jl * 64 + cc);
        }
    }

#pragma unroll
    for (int u = 0; u < 4; ++u) {
        int blk2 = bid4 + u;
        int blk = blk2 >> 1, half = blk2 & 1;
        int b = blk >> 7, i = blk & 127;
        int j0 = half << 6;

        // ---- (1) issue this unit's xb loads (latency hides under va pack+reduce)
        float4 vb[8];
#pragma unroll
        for (int p = 0; p < 8; ++p) {
            int jl = 32 * w + p * 4 + jq;
            vb[p] = *reinterpret_cast<const float4*>(
                x2 + ((size_t)((b * 128 + j0 + jl) * 128 + i)) * 64 + cc);
        }

        // ---- (2) consume vaP: max/min partials + cvt_pk pack -> Ald k=0..63
        f32x4 mx = {0.f, 0.f, 0.f, 0.f}, mn = {1.f, 1.f, 1.f, 1.f};
#pragma unroll
        for (int p = 0; p < 8; ++p) {
            int jl = 32 * w + p * 4 + jq;
            bool ok = (j0 + jl != i);
            mx.x = fmaxf(mx.x, ok ? vaP[p].x : 0.0f); mx.y = fmaxf(mx.y, ok ? vaP[p].y : 0.0f);
            mx.z = fmaxf(mx.z, ok ? vaP[p].z : 0.0f); mx.w = fmaxf(mx.w, ok ? vaP[p].w : 0.0f);
            mn.x = fminf(mn.x, ok ? vaP[p].x : 1.0f); mn.y = fminf(mn.y, ok ? vaP[p].y : 1.0f);
            mn.z = fminf(mn.z, ok ? vaP[p].z : 1.0f); mn.w = fminf(mn.w, ok ? vaP[p].w : 1.0f);
            uint2 uu = pk4(vaP[p]);
            *reinterpret_cast<uint2*>(&Ald[jl * 128 + (cc ^ ((jl & 7) << 3))]) = uu;
        }
        // reduce partials across the 4 jq groups; store to ws
#pragma unroll
        for (int d = 16; d <= 32; d <<= 1) {
            mx.x = fmaxf(mx.x, __shfl_xor(mx.x, d)); mx.y = fmaxf(mx.y, __shfl_xor(mx.y, d));
            mx.z = fmaxf(mx.z, __shfl_xor(mx.z, d)); mx.w = fmaxf(mx.w, __shfl_xor(mx.w, d));
            mn.x = fminf(mn.x, __shfl_xor(mn.x, d)); mn.y = fminf(mn.y, __shfl_xor(mn.y, d));
            mn.z = fminf(mn.z, __shfl_xor(mn.z, d)); mn.w = fminf(mn.w, __shfl_xor(mn.w, d));
        }
        if (lane < 16) {
            int slot = blk * 4 + half * 2 + w;
            *reinterpret_cast<f32x4*>(&pmax_ws[slot * 64 + cc]) = mx;
            *reinterpret_cast<f32x4*>(&pmin_ws[slot * 64 + cc]) = mn;
        }

        // ---- (3) prefetch NEXT unit's xa (flies under pack + MFMA + epilogue)
        if (u < 3) {
            int nblk2 = bid4 + u + 1;
            int nblk = nblk2 >> 1, nhalf = nblk2 & 1;
            const float* nsrc = x2 + (size_t)nblk * (NDIM * CDIM) + ((nhalf << 6) * 64);
#pragma unroll
            for (int p = 0; p < 8; ++p) {
                int jl = 32 * w + p * 4 + jq;
                vaP[p] = *reinterpret_cast<const float4*>(nsrc + jl * 64 + cc);
            }
        }

        // ---- (4) consume vb: cvt_pk pack -> Ald k=64..127
#pragma unroll
        for (int p = 0; p < 8; ++p) {
            int jl = 32 * w + p * 4 + jq;
            uint2 uu = pk4(vb[p]);
            *reinterpret_cast<uint2*>(&Ald[jl * 128 + ((64 + cc) ^ ((jl & 7) << 3))]) = uu;
        }

        // ---- (5) B fragments + MFMA (wave-local LDS fence; no barrier)
        f32x4 acc[2][4];
#pragma unroll
        for (int m = 0; m < 2; ++m)
#pragma unroll
            for (int nt = 0; nt < 4; ++nt) acc[m][nt] = (f32x4){0.f, 0.f, 0.f, 0.f};

        s16x8 bf01[2][4];
#pragma unroll
        for (int ks = 0; ks < 2; ++ks)
#pragma unroll
            for (int nt = 0; nt < 4; ++nt) {
                int n = nt * 16 + l15;
                bf01[ks][nt] = *reinterpret_cast<const s16x8*>(
                    WT + n * 128 + ks * 32 + jq * 8);
            }

        asm volatile("s_waitcnt lgkmcnt(0)" ::: "memory");
        __builtin_amdgcn_sched_barrier(0);

#pragma unroll
        for (int ks = 0; ks < 2; ++ks) {
#pragma unroll
            for (int m = 0; m < 2; ++m) {
                int rowl = 32 * w + m * 16 + l15;
                int u8 = (ks * 4 + jq) * 8;
                s16x8 afrag = *reinterpret_cast<const s16x8*>(
                    &Ald[rowl * 128 + (u8 ^ ((rowl & 7) << 3))]);
#pragma unroll
                for (int nt = 0; nt < 4; ++nt)
                    acc[m][nt] = __builtin_amdgcn_mfma_f32_16x16x32_bf16(
                        afrag, bf01[ks][nt], acc[m][nt], 0, 0, 0);
            }
        }
        s16x8 bf23[2][4];
#pragma unroll
        for (int ks = 0; ks < 2; ++ks)
#pragma unroll
            for (int nt = 0; nt < 4; ++nt) {
                int n = nt * 16 + l15;
                bf23[ks][nt] = *reinterpret_cast<const s16x8*>(
                    WT + n * 128 + (2 + ks) * 32 + jq * 8);
            }
#pragma unroll
        for (int ks = 0; ks < 2; ++ks) {
#pragma unroll
            for (int m = 0; m < 2; ++m) {
                int rowl = 32 * w + m * 16 + l15;
                int u8 = ((2 + ks) * 4 + jq) * 8;
                s16x8 afrag = *reinterpret_cast<const s16x8*>(
                    &Ald[rowl * 128 + (u8 ^ ((rowl & 7) << 3))]);
#pragma unroll
                for (int nt = 0; nt < 4; ++nt)
                    acc[m][nt] = __builtin_amdgcn_mfma_f32_16x16x32_bf16(
                        afrag, bf23[ks][nt], acc[m][nt], 0, 0, 0);
            }
        }

        // ---- (6) epilogue: D row=(lane>>4)*4+r (local j), col=lane&15 (c)
        const float* PAi = PA + blk * 64;
        const float* PBb = PB + b * 128 * 64;
        float* outBase = out2 + (size_t)blk * (NDIM * CDIM);
#pragma unroll
        for (int m = 0; m < 2; ++m) {
            int jt = j0 + 32 * w + m * 16 + jq * 4;
#pragma unroll
            for (int nt = 0; nt < 4; ++nt) {
                int cp = nt * 16 + l15;
                float pav = PAi[cp];
#pragma unroll
                for (int r = 0; r < 4; ++r) {
                    int j = jt + r;
                    outBase[j * 64 + cp] = sigmoidf_(acc[m][nt][r] + pav + PBb[j * 64 + cp]);
                }
            }
        }
    }
}

// ---- out1 tail: combine 4 ws partials + 200x64 matvec
__global__ __launch_bounds__(256) void k_out1_tail(const float* __restrict__ x0,
        const float* __restrict__ x1, const float* __restrict__ W1,
        const float* __restrict__ b1, const float* __restrict__ pmax_ws,
        const float* __restrict__ pmin_ws, float* __restrict__ out1) {
    int blk = blockIdx.x;          // b*128 + i
    int t = threadIdx.x;
    int c = t & 63, g = t >> 6;
    __shared__ float sf[200], spart[4][64];
    if (t < 64) {
        float M = 0.f, m = 1.f;
#pragma unroll
        for (int s = 0; s < 4; ++s) {
            M = fmaxf(M, pmax_ws[(blk * 4 + s) * 64 + c]);
            m = fminf(m, pmin_ws[(blk * 4 + s) * 64 + c]);
        }
        sf[72 + c] = M; sf[136 + c] = m;
        sf[8 + c] = x1[blk * 64 + c];
        if (c < 8) sf[c] = x0[(blk >> 7) * 8 + c];
    }
    __syncthreads();
    {
        float a = 0.f;
#pragma unroll 10
        for (int k = g * 50; k < g * 50 + 50; ++k) a += sf[k] * W1[k * 64 + c];
        spart[g][c] = a;
    }
    __syncthreads();
    if (t < 64) {
        out1[blk * 64 + c] = sigmoidf_(
            spart[0][c] + spart[1][c] + spart[2][c] + spart[3][c] + b1[c]);
    }
}

extern "C" void kernel_launch(void* const* d_in, const int* in_sizes, int n_in,
                              void* d_out, int out_size, void* d_ws, size_t ws_size,
                              hipStream_t stream) {
    const float* x0 = (const float*)d_in[0];
    const float* x1 = (const float*)d_in[1];
    const float* x2 = (const float*)d_in[2];
    const float* W0 = (const float*)d_in[3];
    const float* b0 = (const float*)d_in[4];
    const float* W1 = (const float*)d_in[5];
    const float* b1 = (const float*)d_in[6];
    const float* W2 = (const float*)d_in[7];
    const float* b2 = (const float*)d_in[8];

    float* out0 = (float*)d_out;
    float* out1 = out0 + 16 * 64;
    float* out2 = out1 + 16 * 128 * 64;

    float* PA = (float*)d_ws;                            // 16*128*64 f32 (512KB)
    float* PB = PA + 16 * 128 * 64;                      // 512KB
    unsigned short* WT = (unsigned short*)(PB + 16 * 128 * 64);  // 16KB
    float* pmax_ws = (float*)(WT + 64 * 128);            // 2048*4*64 f32 (2MB)
    float* pmin_ws = pmax_ws + 2048 * 4 * 64;            // 2MB

    k_prep<<<560, 256, 0, stream>>>(x0, x1, W0, b0, W2, b2, PA, PB, WT, out0);
    k_main<<<1024, 128, 0, stream>>>(x2, WT, PA, PB, pmax_ws, pmin_ws, out2);
    k_out1_tail<<<2048, 256, 0, stream>>>(x0, x1, W1, b1, pmax_ws, pmin_ws, out1);
}

// Round 12
// 51.765 us; speedup vs baseline: 1.6345x; 1.6345x over previous
//
#include <hip/hip_runtime.h>
#include <hip/hip_bf16.h>
#include <cstdint>

// DLM breadth-2 forward. B=16, n=128, C=64.
// out = [out0 (16*64) | out1 (16*128*64) | out2 (16*128*128*64)], fp32.
//
// out2[b,i,j,c] = sigmoid( PA[b,i,c] + PB[b,j,c]
//                          + x2[b,i,j,:]·W2[64:128,c] + x2[b,j,i,:]·W2[192:256,c] )
// with PA = x1·W2[0:64] + b2, PB = x1·W2[128:192]  (precomputed).
//
// k_main == R8 structure byte-for-byte, plus ONE change: XCD-chunked
// bijective block swizzle (4096 = 8 XCD x 512). Each XCD owns 2 full
// batches b -> its concurrent blocks' scattered xb column-reads cover a
// contiguous i-range (DRAM page locality) and hit xa-fetched lines in
// the same XCD L2 instead of a remote one.

#define NDIM 128
#define CDIM 64

typedef float f32x4 __attribute__((ext_vector_type(4)));
typedef short s16x8 __attribute__((ext_vector_type(8)));

__device__ __forceinline__ unsigned short f2bf(float f) {
    union { float f; unsigned int u; } v; v.f = f;
    unsigned int u = v.u;
    return (unsigned short)((u + 0x7FFFu + ((u >> 16) & 1u)) >> 16);  // RNE
}
__device__ __forceinline__ float sigmoidf_(float x) {
    return 1.0f / (1.0f + __expf(-x));
}
// pack float4 -> 4 bf16 (RNE) in two v_cvt_pk_bf16_f32
__device__ __forceinline__ uint2 pk4(float4 v) {
    unsigned lo, hi;
    asm("v_cvt_pk_bf16_f32 %0, %1, %2" : "=v"(lo) : "v"(v.x), "v"(v.y));
    asm("v_cvt_pk_bf16_f32 %0, %1, %2" : "=v"(hi) : "v"(v.z), "v"(v.w));
    uint2 r; r.x = lo; r.y = hi; return r;
}

// ---- merged prep: blocks [0,512) -> PA/PB; [512,544) -> WT; [544,560) -> out0
__global__ __launch_bounds__(256) void k_prep(const float* __restrict__ x0,
        const float* __restrict__ x1, const float* __restrict__ W0,
        const float* __restrict__ b0, const float* __restrict__ W2,
        const float* __restrict__ b2, float* __restrict__ PA,
        float* __restrict__ PB, unsigned short* __restrict__ WT,
        float* __restrict__ out0) {
    int bb = blockIdx.x;
    int t = threadIdx.x;
    if (bb < 512) {
        int u = t >> 6, c = t & 63;
        int blk = bb * 4 + u;          // 0..2047
        __shared__ float xv[4][64];
        xv[u][c] = x1[blk * 64 + c];   // wave-local RAW
        float accA = b2[c];
        float accB = 0.f;
#pragma unroll 8
        for (int k = 0; k < 64; ++k) {
            float xk = xv[u][k];
            accA += xk * W2[k * 64 + c];
            accB += xk * W2[(128 + k) * 64 + c];
        }
        PA[blk * 64 + c] = accA;
        PB[blk * 64 + c] = accB;
    } else if (bb < 544) {
        int idx = (bb - 512) * 256 + t;   // 0..8191
        int n = idx >> 7, k = idx & 127;
        int row = (k < 64) ? (64 + k) : (128 + k);
        WT[idx] = f2bf(W2[row * 64 + n]);
    } else {
        int b = bb - 544;
        int lane = t & 63, w = t >> 6;
        int q = lane & 15;
        int jq = lane >> 4;
        __shared__ float pw[4][64], pn[4][64], f0[136], spart[4][64];
        f32x4 mx = {-1e30f, -1e30f, -1e30f, -1e30f};
        f32x4 mn = {1e30f, 1e30f, 1e30f, 1e30f};
#pragma unroll
        for (int p = 0; p < 8; ++p) {
            int j = (w * 4 + jq) + 16 * p;
            float4 v = *reinterpret_cast<const float4*>(
                x1 + ((size_t)(b * 128 + j)) * 64 + q * 4);
            mx.x = fmaxf(mx.x, v.x); mx.y = fmaxf(mx.y, v.y);
            mx.z = fmaxf(mx.z, v.z); mx.w = fmaxf(mx.w, v.w);
            mn.x = fminf(mn.x, v.x); mn.y = fminf(mn.y, v.y);
            mn.z = fminf(mn.z, v.z); mn.w = fminf(mn.w, v.w);
        }
#pragma unroll
        for (int d = 16; d <= 32; d <<= 1) {
            mx.x = fmaxf(mx.x, __shfl_xor(mx.x, d)); mx.y = fmaxf(mx.y, __shfl_xor(mx.y, d));
            mx.z = fmaxf(mx.z, __shfl_xor(mx.z, d)); mx.w = fmaxf(mx.w, __shfl_xor(mx.w, d));
            mn.x = fminf(mn.x, __shfl_xor(mn.x, d)); mn.y = fminf(mn.y, __shfl_xor(mn.y, d));
            mn.z = fminf(mn.z, __shfl_xor(mn.z, d)); mn.w = fminf(mn.w, __shfl_xor(mn.w, d));
        }
        if (lane < 16) {
            *reinterpret_cast<f32x4*>(&pw[w][lane * 4]) = mx;
            *reinterpret_cast<f32x4*>(&pn[w][lane * 4]) = mn;
        }
        __syncthreads();
        if (t < 64) {
            int c = t;
            float M = fmaxf(fmaxf(pw[0][c], pw[1][c]), fmaxf(pw[2][c], pw[3][c]));
            float m = fminf(fminf(pn[0][c], pn[1][c]), fminf(pn[2][c], pn[3][c]));
            f0[8 + c] = M; f0[72 + c] = m;
            if (c < 8) f0[c] = x0[b * 8 + c];
        }
        __syncthreads();
        {
            int g = t >> 6, c = t & 63;
            float acc = 0.f;
#pragma unroll
            for (int k = g * 34; k < g * 34 + 34; ++k) acc += f0[k] * W0[k * 64 + c];
            spart[g][c] = acc;
        }
        __syncthreads();
        if (t < 64) {
            int c = t;
            out0[b * 64 + c] = sigmoidf_(
                spart[0][c] + spart[1][c] + spart[2][c] + spart[3][c] + b0[c]);
        }
    }
}

// ---- main: one block per (b,i,half). 2 waves, 16KB LDS, barrier-free.
__global__ __launch_bounds__(128) void k_main(const float* __restrict__ x2,
        const unsigned short* __restrict__ WT,
        const float* __restrict__ PA, const float* __restrict__ PB,
        float* __restrict__ pmax_ws, float* __restrict__ pmin_ws,
        float* __restrict__ out2) {
    // XCD-chunked bijective swizzle: 4096 = 8 XCD * 512 (one change vs R8)
    int bid = ((blockIdx.x & 7) << 9) | (blockIdx.x >> 3);
    int blk = bid >> 1, half = bid & 1;
    int b = blk >> 7, i = blk & 127;
    int j0 = half << 6;
    int t = threadIdx.x;
    int lane = t & 63, w = t >> 6; // w in 0..1
    int jq = lane >> 4;            // 0..3
    int cc = (lane & 15) * 4;      // c-quad base

    __shared__ __align__(16) unsigned short Ald[64 * 128];   // 16KB, XOR-swizzled

    const float* xaSrc = x2 + (size_t)blk * (NDIM * CDIM);

    // ---- phase 1: xa rows (x2[b,i,j,:]) -> regs
    float4 va[8];
#pragma unroll
    for (int p = 0; p < 8; ++p) {
        int jl = 32 * w + p * 4 + jq;
        va[p] = *reinterpret_cast<const float4*>(xaSrc + (j0 + jl) * 64 + cc);
    }
    // consume xa: max/min partials + cvt_pk pack -> LDS k=0..63
    f32x4 mx = {0.f, 0.f, 0.f, 0.f}, mn = {1.f, 1.f, 1.f, 1.f};  // diag fill values
#pragma unroll
    for (int p = 0; p < 8; ++p) {
        int jl = 32 * w + p * 4 + jq;
        bool ok = (j0 + jl != i);
        mx.x = fmaxf(mx.x, ok ? va[p].x : 0.0f); mx.y = fmaxf(mx.y, ok ? va[p].y : 0.0f);
        mx.z = fmaxf(mx.z, ok ? va[p].z : 0.0f); mx.w = fmaxf(mx.w, ok ? va[p].w : 0.0f);
        mn.x = fminf(mn.x, ok ? va[p].x : 1.0f); mn.y = fminf(mn.y, ok ? va[p].y : 1.0f);
        mn.z = fminf(mn.z, ok ? va[p].z : 1.0f); mn.w = fminf(mn.w, ok ? va[p].w : 1.0f);
        uint2 u = pk4(va[p]);
        *reinterpret_cast<uint2*>(&Ald[jl * 128 + (cc ^ ((jl & 7) << 3))]) = u;
    }

    // ---- issue xb loads NOW (latency hides under reduce + bfrag + MFMA ks01)
    float4 vb[8];
#pragma unroll
    for (int p = 0; p < 8; ++p) {
        int jl = 32 * w + p * 4 + jq;
        vb[p] = *reinterpret_cast<const float4*>(
            x2 + ((size_t)((b * 128 + j0 + jl) * 128 + i)) * 64 + cc);
    }

    // ---- reduce partials across the 4 jq groups; store to ws
#pragma unroll
    for (int d = 16; d <= 32; d <<= 1) {
        mx.x = fmaxf(mx.x, __shfl_xor(mx.x, d)); mx.y = fmaxf(mx.y, __shfl_xor(mx.y, d));
        mx.z = fmaxf(mx.z, __shfl_xor(mx.z, d)); mx.w = fmaxf(mx.w, __shfl_xor(mx.w, d));
        mn.x = fminf(mn.x, __shfl_xor(mn.x, d)); mn.y = fminf(mn.y, __shfl_xor(mn.y, d));
        mn.z = fminf(mn.z, __shfl_xor(mn.z, d)); mn.w = fminf(mn.w, __shfl_xor(mn.w, d));
    }
    if (lane < 16) {
        int slot = blk * 4 + half * 2 + w;
        *reinterpret_cast<f32x4*>(&pmax_ws[slot * 64 + cc]) = mx;
        *reinterpret_cast<f32x4*>(&pmin_ws[slot * 64 + cc]) = mn;
    }

    // ---- B fragments for ks=0,1 (WT L1/L2-hot)
    s16x8 bf01[2][4];
#pragma unroll
    for (int ks = 0; ks < 2; ++ks)
#pragma unroll
        for (int nt = 0; nt < 4; ++nt) {
            int n = nt * 16 + (lane & 15);
            bf01[ks][nt] = *reinterpret_cast<const s16x8*>(WT + n * 128 + ks * 32 + jq * 8);
        }

    f32x4 acc[2][4];
#pragma unroll
    for (int m = 0; m < 2; ++m)
#pragma unroll
        for (int nt = 0; nt < 4; ++nt) acc[m][nt] = (f32x4){0.f, 0.f, 0.f, 0.f};

    // wave-local LDS producer/consumer: xa writes complete before reads.
    asm volatile("s_waitcnt lgkmcnt(0)" ::: "memory");
    __builtin_amdgcn_sched_barrier(0);

    // ---- MFMA ks=0,1 over own local rows (xa half of LDS)
#pragma unroll
    for (int ks = 0; ks < 2; ++ks) {
#pragma unroll
        for (int m = 0; m < 2; ++m) {
            int rowl = 32 * w + m * 16 + (lane & 15);
            int u8 = (ks * 4 + jq) * 8;            // ushort offset of 16B chunk
            s16x8 afrag = *reinterpret_cast<const s16x8*>(
                &Ald[rowl * 128 + (u8 ^ ((rowl & 7) << 3))]);
#pragma unroll
            for (int nt = 0; nt < 4; ++nt)
                acc[m][nt] = __builtin_amdgcn_mfma_f32_16x16x32_bf16(
                    afrag, bf01[ks][nt], acc[m][nt], 0, 0, 0);
        }
    }

    // ---- consume xb: cvt_pk pack -> LDS k=64..127
#pragma unroll
    for (int p = 0; p < 8; ++p) {
        int jl = 32 * w + p * 4 + jq;
        uint2 u = pk4(vb[p]);
        *reinterpret_cast<uint2*>(&Ald[jl * 128 + ((64 + cc) ^ ((jl & 7) << 3))]) = u;
    }
    // B fragments for ks=2,3
    s16x8 bf23[2][4];
#pragma unroll
    for (int ks = 0; ks < 2; ++ks)
#pragma unroll
        for (int nt = 0; nt < 4; ++nt) {
            int n = nt * 16 + (lane & 15);
            bf23[ks][nt] = *reinterpret_cast<const s16x8*>(
                WT + n * 128 + (2 + ks) * 32 + jq * 8);
        }

    asm volatile("s_waitcnt lgkmcnt(0)" ::: "memory");
    __builtin_amdgcn_sched_barrier(0);

    // ---- MFMA ks=2,3 (xb half of LDS)
#pragma unroll
    for (int ks = 0; ks < 2; ++ks) {
#pragma unroll
        for (int m = 0; m < 2; ++m) {
            int rowl = 32 * w + m * 16 + (lane & 15);
            int u8 = ((2 + ks) * 4 + jq) * 8;
            s16x8 afrag = *reinterpret_cast<const s16x8*>(
                &Ald[rowl * 128 + (u8 ^ ((rowl & 7) << 3))]);
#pragma unroll
            for (int nt = 0; nt < 4; ++nt)
                acc[m][nt] = __builtin_amdgcn_mfma_f32_16x16x32_bf16(
                    afrag, bf23[ks][nt], acc[m][nt], 0, 0, 0);
        }
    }

    // ---- out2 epilogue: D row=(lane>>4)*4+r (local j), col=lane&15 (c)
    const float* PAi = PA + blk * 64;
    const float* PBb = PB + b * 128 * 64;
    float* outBase = out2 + (size_t)blk * (NDIM * CDIM);
#pragma unroll
    for (int m = 0; m < 2; ++m) {
        int jt = j0 + 32 * w + m * 16 + jq * 4;
#pragma unroll
        for (int nt = 0; nt < 4; ++nt) {
            int cp = nt * 16 + (lane & 15);
            float pav = PAi[cp];
#pragma unroll
            for (int r = 0; r < 4; ++r) {
                int j = jt + r;
                outBase[j * 64 + cp] = sigmoidf_(acc[m][nt][r] + pav + PBb[j * 64 + cp]);
            }
        }
    }
}

// ---- out1 tail: combine 4 ws partials + 200x64 matvec
__global__ __launch_bounds__(256) void k_out1_tail(const float* __restrict__ x0,
        const float* __restrict__ x1, const float* __restrict__ W1,
        const float* __restrict__ b1, const float* __restrict__ pmax_ws,
        const float* __restrict__ pmin_ws, float* __restrict__ out1) {
    int blk = blockIdx.x;          // b*128 + i
    int t = threadIdx.x;
    int c = t & 63, g = t >> 6;
    __shared__ float sf[200], spart[4][64];
    if (t < 64) {
        float M = 0.f, m = 1.f;
#pragma unroll
        for (int s = 0; s < 4; ++s) {
            M = fmaxf(M, pmax_ws[(blk * 4 + s) * 64 + c]);
            m = fminf(m, pmin_ws[(blk * 4 + s) * 64 + c]);
        }
        sf[72 + c] = M; sf[136 + c] = m;
        sf[8 + c] = x1[blk * 64 + c];
        if (c < 8) sf[c] = x0[(blk >> 7) * 8 + c];
    }
    __syncthreads();
    {
        float a = 0.f;
#pragma unroll 10
        for (int k = g * 50; k < g * 50 + 50; ++k) a += sf[k] * W1[k * 64 + c];
        spart[g][c] = a;
    }
    __syncthreads();
    if (t < 64) {
        out1[blk * 64 + c] = sigmoidf_(
            spart[0][c] + spart[1][c] + spart[2][c] + spart[3][c] + b1[c]);
    }
}

extern "C" void kernel_launch(void* const* d_in, const int* in_sizes, int n_in,
                              void* d_out, int out_size, void* d_ws, size_t ws_size,
                              hipStream_t stream) {
    const float* x0 = (const float*)d_in[0];
    const float* x1 = (const float*)d_in[1];
    const float* x2 = (const float*)d_in[2];
    const float* W0 = (const float*)d_in[3];
    const float* b0 = (const float*)d_in[4];
    const float* W1 = (const float*)d_in[5];
    const float* b1 = (const float*)d_in[6];
    const float* W2 = (const float*)d_in[7];
    const float* b2 = (const float*)d_in[8];

    float* out0 = (float*)d_out;
    float* out1 = out0 + 16 * 64;
    float* out2 = out1 + 16 * 128 * 64;

    float* PA = (float*)d_ws;                            // 16*128*64 f32 (512KB)
    float* PB = PA + 16 * 128 * 64;                      // 512KB
    unsigned short* WT = (unsigned short*)(PB + 16 * 128 * 64);  // 16KB
    float* pmax_ws = (float*)(WT + 64 * 128);            // 2048*4*64 f32 (2MB)
    float* pmin_ws = pmax_ws + 2048 * 4 * 64;            // 2MB

    k_prep<<<560, 256, 0, stream>>>(x0, x1, W0, b0, W2, b2, PA, PB, WT, out0);
    k_main<<<4096, 128, 0, stream>>>(x2, WT, PA, PB, pmax_ws, pmin_ws, out2);
    k_out1_tail<<<2048, 256, 0, stream>>>(x0, x1, W1, b1, pmax_ws, pmin_ws, out1);
}